// Round 1
// baseline (442.608 us; speedup 1.0000x reference)
//
#include <hip/hip_runtime.h>
#include <hip/hip_bf16.h>
#include <stdint.h>

#define TOKENS 8192
#define IN_F   4096
#define OUT_F  4096

typedef __attribute__((ext_vector_type(4))) float  f32x4;
typedef __attribute__((ext_vector_type(8))) __bf16 bf16x8;

__device__ __forceinline__ unsigned short f2bf(float f) {
    union { float f; uint32_t u; } c; c.f = f;
    uint32_t u = c.u;
    u += 0x7fffu + ((u >> 16) & 1);   // round-to-nearest-even
    return (unsigned short)(u >> 16);
}

__device__ __forceinline__ void load_lds_16(const void* gptr, void* lptr) {
    __builtin_amdgcn_global_load_lds(
        (const __attribute__((address_space(1))) unsigned int*)gptr,
        (__attribute__((address_space(3))) unsigned int*)lptr, 16, 0, 0);
}

// ---------------- prep: x fp32 -> bf16 ----------------
__global__ __launch_bounds__(256) void cvt_x_kernel(const float* __restrict__ x,
                                                    unsigned short* __restrict__ xb, int n4) {
    int i = blockIdx.x * blockDim.x + threadIdx.x;
    int stride = gridDim.x * blockDim.x;
    for (; i < n4; i += stride) {
        float4 v = ((const float4*)x)[i];
        ushort4 o;
        o.x = f2bf(v.x); o.y = f2bf(v.y); o.z = f2bf(v.z); o.w = f2bf(v.w);
        ((ushort4*)xb)[i] = o;
    }
}

// ---------------- prep: W_eff = W*(1+mask) fp32 -> bf16 ----------------
__global__ __launch_bounds__(256) void cvt_w_kernel(const float* __restrict__ w,
                                                    const int* __restrict__ mask,
                                                    unsigned short* __restrict__ wb) {
    const int n4 = OUT_F * IN_F / 4;
    int i = blockIdx.x * blockDim.x + threadIdx.x;
    int stride = gridDim.x * blockDim.x;
    for (; i < n4; i += stride) {
        int elem = i * 4;
        int o = elem >> 12;          // / IN_F
        int k = elem & (IN_F - 1);
        int mb = mask[(o >> 4) * (IN_F / 16) + (k >> 4)];
        float s = mb ? 2.0f : 1.0f;
        float4 v = ((const float4*)w)[i];
        ushort4 ov;
        ov.x = f2bf(v.x * s); ov.y = f2bf(v.y * s);
        ov.z = f2bf(v.z * s); ov.w = f2bf(v.w * s);
        ((ushort4*)wb)[i] = ov;
    }
}

// ---------------- main bf16 MFMA GEMM: C = A @ B^T + bias ----------------
// A [TOKENS][IN_F] bf16, B [OUT_F][IN_F] bf16 (K-contiguous both), C fp32.
#define BM 128
#define BN 128
#define BK 64

__global__ __launch_bounds__(256, 1) void gemm_kernel(const unsigned short* __restrict__ A,
                                                      const unsigned short* __restrict__ B,
                                                      const float* __restrict__ bias,
                                                      float* __restrict__ C) {
    __shared__ __align__(16) unsigned short As[BM * BK];
    __shared__ __align__(16) unsigned short Bs[BN * BK];

    const int nwg = (TOKENS / BM) * (OUT_F / BN);   // 2048, divisible by 8
    int bid = blockIdx.x;
    int swz = (bid & 7) * (nwg >> 3) + (bid >> 3);  // XCD-aware swizzle
    const int tiles_n = OUT_F / BN;                 // 32
    int tm = swz / tiles_n;
    int tn = swz % tiles_n;
    const int t0 = tm * BM;
    const int o0 = tn * BN;

    int tid  = threadIdx.x;
    int lane = tid & 63;
    int w    = tid >> 6;            // wave 0..3
    int wr   = w >> 1, wc = w & 1;  // wave -> 64x64 quadrant

    // staging: wave w owns rows [w*32, w*32+32) of both tiles
    const int arow_base = w * 32;
    const int lrow   = lane >> 3;   // 0..7
    const int lchunk = lane & 7;    // 16B chunk within 128B row

    f32x4 acc[4][4];
#pragma unroll
    for (int i = 0; i < 4; ++i)
#pragma unroll
        for (int j = 0; j < 4; ++j) acc[i][j] = (f32x4)0.0f;

    const int NT = IN_F / BK;       // 64
    for (int kt = 0; kt < NT; ++kt) {
        int k0 = kt * BK;
#pragma unroll
        for (int i = 0; i < 4; ++i) {
            int row = arow_base + i * 8;            // uniform per wave
            const unsigned short* ga = A + (size_t)(t0 + row + lrow) * IN_F + k0 + lchunk * 8;
            load_lds_16(ga, &As[row * BK]);
            const unsigned short* gb = B + (size_t)(o0 + row + lrow) * IN_F + k0 + lchunk * 8;
            load_lds_16(gb, &Bs[row * BK]);
        }
        __syncthreads();   // drains vmcnt: LDS tiles ready

#pragma unroll
        for (int ks = 0; ks < 2; ++ks) {
            bf16x8 af[4], bf[4];
#pragma unroll
            for (int mf = 0; mf < 4; ++mf) {
                int r = wr * 64 + mf * 16 + (lane & 15);
                af[mf] = *(const bf16x8*)&As[r * BK + ks * 32 + (lane >> 4) * 8];
            }
#pragma unroll
            for (int nf = 0; nf < 4; ++nf) {
                int r = wc * 64 + nf * 16 + (lane & 15);
                bf[nf] = *(const bf16x8*)&Bs[r * BK + ks * 32 + (lane >> 4) * 8];
            }
#pragma unroll
            for (int mf = 0; mf < 4; ++mf)
#pragma unroll
                for (int nf = 0; nf < 4; ++nf)
                    acc[mf][nf] = __builtin_amdgcn_mfma_f32_16x16x32_bf16(af[mf], bf[nf], acc[mf][nf], 0, 0, 0);
        }
        __syncthreads();   // protect LDS before next stage
    }

    // epilogue: C/D layout col = lane&15, row = (lane>>4)*4 + reg  [m89/m91]
    int col   = lane & 15;
    int rbase = (lane >> 4) * 4;
#pragma unroll
    for (int nf = 0; nf < 4; ++nf) {
        int o = o0 + wc * 64 + nf * 16 + col;
        float bv = bias[o];
#pragma unroll
        for (int mf = 0; mf < 4; ++mf) {
            int t = t0 + wr * 64 + mf * 16 + rbase;
#pragma unroll
            for (int r = 0; r < 4; ++r) {
                C[(size_t)(t + r) * OUT_F + o] = acc[mf][nf][r] + bv;
            }
        }
    }
}

// ---------------- fp32 fallback (only if ws too small) ----------------
__global__ __launch_bounds__(256) void gemm_f32_fallback(const float* __restrict__ x,
                                                         const float* __restrict__ w,
                                                         const float* __restrict__ bias,
                                                         const int* __restrict__ mask,
                                                         float* __restrict__ out) {
    __shared__ float As[64][17];
    __shared__ float Bs[64][17];
    int bid = blockIdx.x;
    const int tiles_n = OUT_F / 64;
    int tm = bid / tiles_n, tn = bid % tiles_n;
    int t0 = tm * 64, o0 = tn * 64;
    int tid = threadIdx.x;
    int tx = tid & 15, ty = tid >> 4;
    int lrow = tid >> 2, lc4 = (tid & 3) * 4;
    float acc[4][4] = {};
    for (int k0 = 0; k0 < IN_F; k0 += 16) {
        float4 av = *(const float4*)&x[(size_t)(t0 + lrow) * IN_F + k0 + lc4];
        float4 bv = *(const float4*)&w[(size_t)(o0 + lrow) * IN_F + k0 + lc4];
        int mb = mask[((o0 + lrow) >> 4) * (IN_F / 16) + ((k0 + lc4) >> 4)];
        float s = mb ? 2.0f : 1.0f;
        As[lrow][lc4 + 0] = av.x; As[lrow][lc4 + 1] = av.y;
        As[lrow][lc4 + 2] = av.z; As[lrow][lc4 + 3] = av.w;
        Bs[lrow][lc4 + 0] = bv.x * s; Bs[lrow][lc4 + 1] = bv.y * s;
        Bs[lrow][lc4 + 2] = bv.z * s; Bs[lrow][lc4 + 3] = bv.w * s;
        __syncthreads();
#pragma unroll
        for (int kk = 0; kk < 16; ++kk) {
            float a[4], b[4];
#pragma unroll
            for (int i = 0; i < 4; ++i) a[i] = As[ty * 4 + i][kk];
#pragma unroll
            for (int j = 0; j < 4; ++j) b[j] = Bs[tx * 4 + j][kk];
#pragma unroll
            for (int i = 0; i < 4; ++i)
#pragma unroll
                for (int j = 0; j < 4; ++j) acc[i][j] += a[i] * b[j];
        }
        __syncthreads();
    }
#pragma unroll
    for (int j = 0; j < 4; ++j) {
        int o = o0 + tx * 4 + j;
        float bv = bias[o];
#pragma unroll
        for (int i = 0; i < 4; ++i)
            out[(size_t)(t0 + ty * 4 + i) * OUT_F + o] = acc[i][j] + bv;
    }
}

extern "C" void kernel_launch(void* const* d_in, const int* in_sizes, int n_in,
                              void* d_out, int out_size, void* d_ws, size_t ws_size,
                              hipStream_t stream) {
    const float* x    = (const float*)d_in[0];
    const float* wgt  = (const float*)d_in[1];
    const float* bias = (const float*)d_in[2];
    const int*   mask = (const int*)d_in[3];
    float* out = (float*)d_out;

    size_t xb_bytes = (size_t)TOKENS * IN_F * 2;
    size_t wb_bytes = (size_t)OUT_F * IN_F * 2;

    if (ws_size >= xb_bytes + wb_bytes) {
        unsigned short* xb = (unsigned short*)d_ws;
        unsigned short* wb = (unsigned short*)((char*)d_ws + xb_bytes);
        hipLaunchKernelGGL(cvt_x_kernel, dim3(2048), dim3(256), 0, stream, x, xb, TOKENS * IN_F / 4);
        hipLaunchKernelGGL(cvt_w_kernel, dim3(1024), dim3(256), 0, stream, wgt, mask, wb);
        hipLaunchKernelGGL(gemm_kernel, dim3((TOKENS / BM) * (OUT_F / BN)), dim3(256), 0, stream,
                           xb, wb, bias, out);
    } else {
        hipLaunchKernelGGL(gemm_f32_fallback, dim3((TOKENS / 64) * (OUT_F / 64)), dim3(256), 0, stream,
                           x, wgt, bias, mask, out);
    }
}

// Round 3
// 280.003 us; speedup vs baseline: 1.5807x; 1.5807x over previous
//
#include <hip/hip_runtime.h>
#include <hip/hip_bf16.h>
#include <stdint.h>

#define TOKENS 8192
#define IN_F   4096
#define OUT_F  4096

typedef __attribute__((ext_vector_type(4))) float  f32x4;
typedef __attribute__((ext_vector_type(8))) __bf16 bf16x8;

__device__ __forceinline__ unsigned short f2bf(float f) {
    union { float f; uint32_t u; } c; c.f = f;
    uint32_t u = c.u;
    u += 0x7fffu + ((u >> 16) & 1);   // round-to-nearest-even
    return (unsigned short)(u >> 16);
}

__device__ __forceinline__ void load_lds_16(const void* gptr, void* lptr) {
    __builtin_amdgcn_global_load_lds(
        (const __attribute__((address_space(1))) unsigned int*)gptr,
        (__attribute__((address_space(3))) unsigned int*)lptr, 16, 0, 0);
}

template<int N> __device__ __forceinline__ void vm_bar() {
    if constexpr (N == 6)      asm volatile("s_waitcnt vmcnt(6)\ns_barrier" ::: "memory");
    else if constexpr (N == 5) asm volatile("s_waitcnt vmcnt(5)\ns_barrier" ::: "memory");
    else if constexpr (N == 4) asm volatile("s_waitcnt vmcnt(4)\ns_barrier" ::: "memory");
    else if constexpr (N == 3) asm volatile("s_waitcnt vmcnt(3)\ns_barrier" ::: "memory");
    else if constexpr (N == 2) asm volatile("s_waitcnt vmcnt(2)\ns_barrier" ::: "memory");
    else if constexpr (N == 1) asm volatile("s_waitcnt vmcnt(1)\ns_barrier" ::: "memory");
    else                       asm volatile("s_waitcnt vmcnt(0)\ns_barrier" ::: "memory");
}

// ---------------- prep: x fp32 -> bf16 ----------------
__global__ __launch_bounds__(256) void cvt_x_kernel(const float* __restrict__ x,
                                                    unsigned short* __restrict__ xb, int n4) {
    int i = blockIdx.x * blockDim.x + threadIdx.x;
    int stride = gridDim.x * blockDim.x;
    for (; i < n4; i += stride) {
        float4 v = ((const float4*)x)[i];
        ushort4 o;
        o.x = f2bf(v.x); o.y = f2bf(v.y); o.z = f2bf(v.z); o.w = f2bf(v.w);
        ((ushort4*)xb)[i] = o;
    }
}

// ---------------- prep: W_eff = W*(1+mask) fp32 -> bf16 ----------------
__global__ __launch_bounds__(256) void cvt_w_kernel(const float* __restrict__ w,
                                                    const int* __restrict__ mask,
                                                    unsigned short* __restrict__ wb) {
    const int n4 = OUT_F * IN_F / 4;
    int i = blockIdx.x * blockDim.x + threadIdx.x;
    int stride = gridDim.x * blockDim.x;
    for (; i < n4; i += stride) {
        int elem = i * 4;
        int o = elem >> 12;
        int k = elem & (IN_F - 1);
        int mb = mask[(o >> 4) * (IN_F / 16) + (k >> 4)];
        float s = mb ? 2.0f : 1.0f;
        float4 v = ((const float4*)w)[i];
        ushort4 ov;
        ov.x = f2bf(v.x * s); ov.y = f2bf(v.y * s);
        ov.z = f2bf(v.z * s); ov.w = f2bf(v.w * s);
        ((ushort4*)wb)[i] = ov;
    }
}

// ---------------- 256x256 8-wave 4-phase pipelined bf16 GEMM ----------------
// C[t][o] = sum_k A[t][k]*B[o][k] + bias[o]; A,B bf16 K-contiguous, C fp32.
#define BM 256
#define BN 256
#define BK 64
#define TILE_SH (BM * BK)   // 16384 shorts = 32KB per tile buffer

#define PHASE_MFMA(P)                                                          \
    {                                                                          \
        bf16x8 b0 = *(const bf16x8*)(pB + boff0 + (P) * 1024);                 \
        bf16x8 b1 = *(const bf16x8*)(pB + boff1 + (P) * 1024);                 \
        __builtin_amdgcn_s_setprio(1);                                         \
        _Pragma("unroll")                                                      \
        for (int mf = 0; mf < 8; ++mf) {                                       \
            acc[mf][P] = __builtin_amdgcn_mfma_f32_16x16x32_bf16(a[mf][0], b0, acc[mf][P], 0, 0, 0); \
            acc[mf][P] = __builtin_amdgcn_mfma_f32_16x16x32_bf16(a[mf][1], b1, acc[mf][P], 0, 0, 0); \
        }                                                                      \
        __builtin_amdgcn_s_setprio(0);                                         \
    }

// Staging issue order per K-tile (matters for vmcnt accounting):
//   A rows 0-63, A 64-127, A 128-191, A 192-255, Bc0, Bc1, Bc2, Bc3
// Bc_j = B-tile rows {q*64 + j*16 .. +16 | q=0..3}  (exactly what phase j's
// MFMA needs). Steady-state waits {3,4,5,6}; peeled last tile {3,2,1,0}.
#define KTILE(STG, V0, V1, V2, V3)                                             \
    {                                                                          \
        vm_bar<V0>();                                                          \
        if (STG) {                                                             \
            load_lds_16(cgA, stA + dA);                                        \
            load_lds_16(cgA + (size_t)64 * IN_F, stA + dA + 4096);             \
        }                                                                      \
        _Pragma("unroll")                                                      \
        for (int mf = 0; mf < 8; ++mf) {                                       \
            a[mf][0] = *(const bf16x8*)(pA + aoff0 + mf * 1024);               \
            a[mf][1] = *(const bf16x8*)(pA + aoff1 + mf * 1024);               \
        }                                                                      \
        PHASE_MFMA(0)                                                          \
        vm_bar<V1>();                                                          \
        if (STG) {                                                             \
            load_lds_16(cgA + (size_t)128 * IN_F, stA + dA + 8192);            \
            load_lds_16(cgA + (size_t)192 * IN_F, stA + dA + 12288);           \
        }                                                                      \
        PHASE_MFMA(1)                                                          \
        vm_bar<V2>();                                                          \
        if (STG) {                                                             \
            load_lds_16(cgB, stB + dB);                                        \
            load_lds_16(cgB + (size_t)16 * IN_F, stB + dB + 1024);             \
        }                                                                      \
        PHASE_MFMA(2)                                                          \
        vm_bar<V3>();                                                          \
        if (STG) {                                                             \
            load_lds_16(cgB + (size_t)32 * IN_F, stB + dB + 2048);             \
            load_lds_16(cgB + (size_t)48 * IN_F, stB + dB + 3072);             \
        }                                                                      \
        PHASE_MFMA(3)                                                          \
    }

__global__ __launch_bounds__(512, 2) void gemm8_kernel(const unsigned short* __restrict__ A,
                                                       const unsigned short* __restrict__ B,
                                                       const float* __restrict__ bias,
                                                       float* __restrict__ C) {
    extern __shared__ __align__(16) unsigned short sm[];   // 128KB dynamic

    const int tid  = threadIdx.x;
    const int lane = tid & 63;
    const int wid  = tid >> 6;       // 0..7
    const int wr   = wid >> 2;       // 0..1 -> 128-row span
    const int wc   = wid & 3;        // 0..3 -> 64-col span

    const int nwg = (TOKENS / BM) * (OUT_F / BN);   // 512, %8==0
    int bid = blockIdx.x;
    int swz = (bid & 7) * (nwg >> 3) + (bid >> 3);  // XCD-aware swizzle
    const int tiles_n = OUT_F / BN;                 // 16
    const int t0 = (swz / tiles_n) * BM;
    const int o0 = (swz % tiles_n) * BN;

    // ---- staging addresses (pre-swizzled global source, linear LDS dest) ----
    // swizzle: 16B-chunk index ^= (row & 7)  [involution; kills the 16-way
    // bank conflict on the stride-128B fragment reads]
    const int srow = tid >> 3;                      // 0..63
    const int lc   = (tid & 7) ^ (srow & 7);
    const unsigned short* gA = A + (size_t)(t0 + srow) * IN_F + lc * 8;
    const int growb = (wid >> 1) * 64 + (wid & 1) * 8 + (lane >> 3);
    const unsigned short* gB = B + (size_t)(o0 + growb) * IN_F + lc * 8;
    const int dA = tid * 8;                         // + r*4096 per A issue
    const int dB = growb * 64 + (tid & 7) * 8;      // + j*1024 per B issue

    // ---- LDS fragment-read offsets (shorts), swizzled to match ----
    const int l15 = lane & 15, q = lane >> 4, l7 = lane & 7;
    const int aoff0 = (wr * 128 + l15) * 64 + (q ^ l7) * 8;        // ks=0
    const int aoff1 = (wr * 128 + l15) * 64 + ((4 + q) ^ l7) * 8;  // ks=1
    const int boff0 = (wc * 64 + l15) * 64 + (q ^ l7) * 8;
    const int boff1 = (wc * 64 + l15) * 64 + ((4 + q) ^ l7) * 8;

    f32x4 acc[8][4];
#pragma unroll
    for (int i = 0; i < 8; ++i)
#pragma unroll
        for (int j = 0; j < 4; ++j) acc[i][j] = (f32x4)0.0f;

    // ---- prologue: stage tile 0 into buffer 0 (canonical issue order) ----
#pragma unroll
    for (int r = 0; r < 4; ++r)
        load_lds_16(gA + (size_t)r * 64 * IN_F, sm + dA + r * 4096);
#pragma unroll
    for (int j = 0; j < 4; ++j)
        load_lds_16(gB + (size_t)j * 16 * IN_F, sm + 2 * TILE_SH + dB + j * 1024);

    bf16x8 a[8][2];

    const unsigned short* cgA = gA + BK;   // staging source: tile kt+1
    const unsigned short* cgB = gB + BK;
    for (int kt = 0; kt < IN_F / BK - 1; ++kt) {
        const int cur = kt & 1, nxt = (kt + 1) & 1;
        const unsigned short* pA = sm + cur * TILE_SH;
        const unsigned short* pB = sm + 2 * TILE_SH + cur * TILE_SH;
        unsigned short* stA = sm + nxt * TILE_SH;
        unsigned short* stB = sm + 2 * TILE_SH + nxt * TILE_SH;
        KTILE(true, 3, 4, 5, 6)
        cgA += BK; cgB += BK;
    }
    {   // peeled last tile (no staging; drain waits 3,2,1,0)
        const unsigned short* pA = sm + TILE_SH;             // (IN_F/BK-1)&1 == 1
        const unsigned short* pB = sm + 2 * TILE_SH + TILE_SH;
        unsigned short* stA = sm;                            // unused (STG=false)
        unsigned short* stB = sm + 2 * TILE_SH;
        KTILE(false, 3, 2, 1, 0)
        (void)stA; (void)stB;
    }

    // ---- epilogue: C/D layout col = lane&15, row = (lane>>4)*4 + reg ----
    float bv[4];
#pragma unroll
    for (int nf = 0; nf < 4; ++nf) bv[nf] = bias[o0 + wc * 64 + nf * 16 + l15];
#pragma unroll
    for (int mf = 0; mf < 8; ++mf) {
        const int t = t0 + wr * 128 + mf * 16 + q * 4;
#pragma unroll
        for (int nf = 0; nf < 4; ++nf) {
            const int o = o0 + wc * 64 + nf * 16 + l15;
#pragma unroll
            for (int r = 0; r < 4; ++r)
                C[(size_t)(t + r) * OUT_F + o] = acc[mf][nf][r] + bv[nf];
        }
    }
}

// ---------------- fp32 fallback (only if ws too small) ----------------
__global__ __launch_bounds__(256) void gemm_f32_fallback(const float* __restrict__ x,
                                                         const float* __restrict__ w,
                                                         const float* __restrict__ bias,
                                                         const int* __restrict__ mask,
                                                         float* __restrict__ out) {
    __shared__ float As[64][17];
    __shared__ float Bs[64][17];
    int bid = blockIdx.x;
    const int tiles_n = OUT_F / 64;
    int tm = bid / tiles_n, tn = bid % tiles_n;
    int t0 = tm * 64, o0 = tn * 64;
    int tid = threadIdx.x;
    int tx = tid & 15, ty = tid >> 4;
    int lrow = tid >> 2, lc4 = (tid & 3) * 4;
    float acc[4][4] = {};
    for (int k0 = 0; k0 < IN_F; k0 += 16) {
        float4 av = *(const float4*)&x[(size_t)(t0 + lrow) * IN_F + k0 + lc4];
        float4 bv = *(const float4*)&w[(size_t)(o0 + lrow) * IN_F + k0 + lc4];
        int mb = mask[((o0 + lrow) >> 4) * (IN_F / 16) + ((k0 + lc4) >> 4)];
        float s = mb ? 2.0f : 1.0f;
        As[lrow][lc4 + 0] = av.x; As[lrow][lc4 + 1] = av.y;
        As[lrow][lc4 + 2] = av.z; As[lrow][lc4 + 3] = av.w;
        Bs[lrow][lc4 + 0] = bv.x * s; Bs[lrow][lc4 + 1] = bv.y * s;
        Bs[lrow][lc4 + 2] = bv.z * s; Bs[lrow][lc4 + 3] = bv.w * s;
        __syncthreads();
#pragma unroll
        for (int kk = 0; kk < 16; ++kk) {
            float av2[4], bv2[4];
#pragma unroll
            for (int i = 0; i < 4; ++i) av2[i] = As[ty * 4 + i][kk];
#pragma unroll
            for (int j = 0; j < 4; ++j) bv2[j] = Bs[tx * 4 + j][kk];
#pragma unroll
            for (int i = 0; i < 4; ++i)
#pragma unroll
                for (int j = 0; j < 4; ++j) acc[i][j] += av2[i] * bv2[j];
        }
        __syncthreads();
    }
#pragma unroll
    for (int j = 0; j < 4; ++j) {
        int o = o0 + tx * 4 + j;
        float bv = bias[o];
#pragma unroll
        for (int i = 0; i < 4; ++i)
            out[(size_t)(t0 + ty * 4 + i) * OUT_F + o] = acc[i][j] + bv;
    }
}

extern "C" void kernel_launch(void* const* d_in, const int* in_sizes, int n_in,
                              void* d_out, int out_size, void* d_ws, size_t ws_size,
                              hipStream_t stream) {
    const float* x    = (const float*)d_in[0];
    const float* wgt  = (const float*)d_in[1];
    const float* bias = (const float*)d_in[2];
    const int*   mask = (const int*)d_in[3];
    float* out = (float*)d_out;

    size_t xb_bytes = (size_t)TOKENS * IN_F * 2;
    size_t wb_bytes = (size_t)OUT_F * IN_F * 2;

    if (ws_size >= xb_bytes + wb_bytes) {
        unsigned short* xb = (unsigned short*)d_ws;
        unsigned short* wb = (unsigned short*)((char*)d_ws + xb_bytes);
        hipLaunchKernelGGL(cvt_x_kernel, dim3(2048), dim3(256), 0, stream, x, xb, TOKENS * IN_F / 4);
        hipLaunchKernelGGL(cvt_w_kernel, dim3(1024), dim3(256), 0, stream, wgt, mask, wb);
        (void)hipFuncSetAttribute((const void*)gemm8_kernel,
                                  hipFuncAttributeMaxDynamicSharedMemorySize, 131072);
        hipLaunchKernelGGL(gemm8_kernel, dim3((TOKENS / BM) * (OUT_F / BN)), dim3(512),
                           131072, stream, xb, wb, bias, out);
    } else {
        hipLaunchKernelGGL(gemm_f32_fallback, dim3((TOKENS / 64) * (OUT_F / 64)), dim3(256), 0, stream,
                           x, wgt, bias, mask, out);
    }
}